// Round 1
// baseline (139.949 us; speedup 1.0000x reference)
//
#include <hip/hip_runtime.h>
#include <hip/hip_bf16.h>
#include <stdint.h>

#define VOCAB 200000
#define EDIM 128
#define NTREES 2048
#define KNODES 511

typedef __attribute__((ext_vector_type(4))) float f32x4;
typedef __attribute__((ext_vector_type(8))) short s16x8;
typedef __attribute__((ext_vector_type(8))) unsigned short u16x8;

__device__ __forceinline__ unsigned short f2bf(float x) {
  unsigned u = __builtin_bit_cast(unsigned, x);
  return (unsigned short)((u + 0x7fffu + ((u >> 16) & 1u)) >> 16);  // RNE
}
__device__ __forceinline__ float bf2f(unsigned short h) {
  unsigned u = ((unsigned)h) << 16;
  return __builtin_bit_cast(float, u);
}

// ---------------- Kernel 1: T[v][d] = bf16( emb[v,:] @ W[:,d] + b[d] ) ----------------
// 256 rows per block, 4 waves, each wave does 64 rows x 128 cols, K=128.
// MFMA 16x16x32 bf16. A from global (row = lane&15, k = 8*(lane>>4)+i).
// B from LDS WT[col][k] (contiguous 8 bf16 per fragment -> ds_read_b128).
// D: row = 4*(lane>>4)+r, col = lane&15  [m89-verified layout].
__global__ __launch_bounds__(256) void proj_kernel(
    const float* __restrict__ emb, const float* __restrict__ W,
    const float* __restrict__ bias, unsigned short* __restrict__ T) {
  __shared__ unsigned short WT[EDIM][136];  // [col][k], pitch 136 keeps 16B alignment
  __shared__ float bsh[EDIM];

  const int tid = threadIdx.x;
  for (int idx = tid; idx < EDIM * EDIM; idx += 256) {
    int k = idx >> 7, n = idx & 127;      // W is [k][n] row-major
    WT[n][k] = f2bf(W[idx]);
  }
  if (tid < EDIM) bsh[tid] = bias[tid];
  __syncthreads();

  const int w = tid >> 6, lane = tid & 63;
  const int q = lane >> 4, cl = lane & 15;
  const long rowbase = (long)blockIdx.x * 256 + (long)w * 64;

  f32x4 acc[4][8];
#pragma unroll
  for (int rt = 0; rt < 4; ++rt)
#pragma unroll
    for (int nt = 0; nt < 8; ++nt) acc[rt][nt] = (f32x4){0.f, 0.f, 0.f, 0.f};

#pragma unroll
  for (int ks = 0; ks < 4; ++ks) {
    const int k0 = ks * 32 + q * 8;
    s16x8 af[4];
#pragma unroll
    for (int rt = 0; rt < 4; ++rt) {
      long r = rowbase + rt * 16 + cl;
      if (r >= VOCAB) r = VOCAB - 1;      // tail clamp (dup loads, stores masked)
      const float* ap = emb + r * EDIM + k0;
      f32x4 a0 = *(const f32x4*)ap;
      f32x4 a1 = *(const f32x4*)(ap + 4);
      u16x8 t;
      t[0] = f2bf(a0[0]); t[1] = f2bf(a0[1]); t[2] = f2bf(a0[2]); t[3] = f2bf(a0[3]);
      t[4] = f2bf(a1[0]); t[5] = f2bf(a1[1]); t[6] = f2bf(a1[2]); t[7] = f2bf(a1[3]);
      af[rt] = __builtin_bit_cast(s16x8, t);
    }
#pragma unroll
    for (int nt = 0; nt < 8; ++nt) {
      s16x8 bf = *(const s16x8*)&WT[nt * 16 + cl][k0];
#pragma unroll
      for (int rt = 0; rt < 4; ++rt)
        acc[rt][nt] = __builtin_amdgcn_mfma_f32_16x16x32_bf16(af[rt], bf, acc[rt][nt], 0, 0, 0);
    }
  }

#pragma unroll
  for (int rt = 0; rt < 4; ++rt) {
#pragma unroll
    for (int nt = 0; nt < 8; ++nt) {
      const int col = nt * 16 + cl;
      const float bv = bsh[col];
#pragma unroll
      for (int r = 0; r < 4; ++r) {
        long row = rowbase + rt * 16 + q * 4 + r;
        if (row < VOCAB) T[row * EDIM + col] = f2bf(acc[rt][nt][r] + bv);
      }
    }
  }
}

// ---------------- Kernel 2: per-tree gather + bottom-up subtree sums + max ----------------
// 1 block = 1 tree. P[node][dim] bf16 (512 rows x 128 dims = 128 KiB).
// Gather 511 T-rows via global_load_lds (dest = uniform base + lane*16).
// In-place level passes: P[m] += P[2m+1] + P[2m+2]; running max covers all nodes.
__global__ __launch_bounds__(512) void tree_kernel(
    const unsigned short* __restrict__ T, const int* __restrict__ tokens,
    float* __restrict__ out) {
  __shared__ unsigned short P[512][EDIM];  // 131072 B

  const int tid = threadIdx.x;
  const int tree = blockIdx.x;
  const int wv = tid >> 6, lane = tid & 63;
  const int q4 = lane >> 4, c16 = lane & 15;

  // --- gather phase: prefetch tokens, then fire 16 LDS-DMA loads per wave ---
  const int* tk = tokens + (long)tree * KNODES;
  int toks[16];
#pragma unroll
  for (int i = 0; i < 16; ++i) {
    int node = (wv * 16 + i) * 4 + q4;
    toks[i] = tk[node > 510 ? 510 : node];  // row 511 = dup of 510, never read
  }
#pragma unroll
  for (int i = 0; i < 16; ++i) {
    const unsigned short* src = T + (long)toks[i] * EDIM + c16 * 8;
    unsigned short* dst = &P[(wv * 16 + i) * 4][0];  // wave-uniform; HW adds lane*16
    __builtin_amdgcn_global_load_lds(
        (const __attribute__((address_space(1))) unsigned int*)src,
        (__attribute__((address_space(3))) unsigned int*)dst, 16, 0, 0);
  }
  __syncthreads();

  // --- tree phase: thread owns dim-chunk c (8 dims), node-group g ---
  const int c = tid & 15, g = tid >> 4;
  float rmax[8];
#pragma unroll
  for (int e = 0; e < 8; ++e) rmax[e] = 0.f;  // 0-init folds the final ReLU clamp

  for (int l = 7; l >= 0; --l) {
    const int cnt = 1 << l;
    for (int j = g; j < cnt; j += 32) {
      const int m = cnt - 1 + j;
      u16x8 pm = *(const u16x8*)&P[m][c * 8];
      u16x8 c1 = *(const u16x8*)&P[2 * m + 1][c * 8];
      u16x8 c2 = *(const u16x8*)&P[2 * m + 2][c * 8];
      u16x8 sp;
#pragma unroll
      for (int e = 0; e < 8; ++e) {
        float x = bf2f(c1[e]), y = bf2f(c2[e]);
        float sv = bf2f(pm[e]) + x + y;
        rmax[e] = fmaxf(rmax[e], fmaxf(fmaxf(x, y), sv));  // children cover leaves
        sp[e] = f2bf(sv);
      }
      *(u16x8*)&P[m][c * 8] = sp;
    }
    __syncthreads();  // write range (< 2^{l+1}-1) disjoint from next level's reads
  }

  // --- max reduce across 32 node-groups (overlay scratch on dead P rows) ---
  float* mb = (float*)&P[0][0];  // 32*128*4 = 16 KiB << 128 KiB
#pragma unroll
  for (int e = 0; e < 8; ++e) mb[g * 128 + c * 8 + e] = rmax[e];
  __syncthreads();
  if (tid < 128) {
    float v = mb[tid];
#pragma unroll 4
    for (int g2 = 1; g2 < 32; ++g2) v = fmaxf(v, mb[g2 * 128 + tid]);
    out[(long)tree * 128 + tid] = v;
  }
}

extern "C" void kernel_launch(void* const* d_in, const int* in_sizes, int n_in,
                              void* d_out, int out_size, void* d_ws, size_t ws_size,
                              hipStream_t stream) {
  const float* emb = (const float*)d_in[0];
  const float* W = (const float*)d_in[1];
  const float* b = (const float*)d_in[2];
  const int* tokens = (const int*)d_in[3];
  // d_in[4..6] (parent/level/batch_id) are structural — recomputed from index math.

  unsigned short* T = (unsigned short*)d_ws;  // 200000*128*2 = 51.2 MB scratch
  float* out = (float*)d_out;

  const int nblk1 = (VOCAB + 255) / 256;  // 782
  proj_kernel<<<nblk1, 256, 0, stream>>>(emb, W, b, T);
  tree_kernel<<<NTREES, 512, 0, stream>>>(T, tokens, out);
}

// Round 2
// 131.292 us; speedup vs baseline: 1.0659x; 1.0659x over previous
//
#include <hip/hip_runtime.h>
#include <hip/hip_bf16.h>
#include <stdint.h>

#define VOCAB 200000
#define EDIM 128
#define NTREES 2048
#define KNODES 511

typedef __attribute__((ext_vector_type(4))) float f32x4;
typedef __attribute__((ext_vector_type(8))) short s16x8;
typedef __attribute__((ext_vector_type(8))) unsigned short u16x8;

__device__ __forceinline__ unsigned short f2bf(float x) {
  unsigned u = __builtin_bit_cast(unsigned, x);
  return (unsigned short)((u + 0x7fffu + ((u >> 16) & 1u)) >> 16);  // RNE
}
__device__ __forceinline__ float bf2f(unsigned short h) {
  unsigned u = ((unsigned)h) << 16;
  return __builtin_bit_cast(float, u);
}

// ---------------- Kernel 1: T[v][d] = bf16( emb[v,:] @ W[:,d] + b[d] ) ----------------
// (unchanged from R1 — kept byte-identical so its counters show up clean next round)
__global__ __launch_bounds__(256) void proj_kernel(
    const float* __restrict__ emb, const float* __restrict__ W,
    const float* __restrict__ bias, unsigned short* __restrict__ T) {
  __shared__ unsigned short WT[EDIM][136];  // [col][k], pitch 136 keeps 16B alignment
  __shared__ float bsh[EDIM];

  const int tid = threadIdx.x;
  for (int idx = tid; idx < EDIM * EDIM; idx += 256) {
    int k = idx >> 7, n = idx & 127;      // W is [k][n] row-major
    WT[n][k] = f2bf(W[idx]);
  }
  if (tid < EDIM) bsh[tid] = bias[tid];
  __syncthreads();

  const int w = tid >> 6, lane = tid & 63;
  const int q = lane >> 4, cl = lane & 15;
  const long rowbase = (long)blockIdx.x * 256 + (long)w * 64;

  f32x4 acc[4][8];
#pragma unroll
  for (int rt = 0; rt < 4; ++rt)
#pragma unroll
    for (int nt = 0; nt < 8; ++nt) acc[rt][nt] = (f32x4){0.f, 0.f, 0.f, 0.f};

#pragma unroll
  for (int ks = 0; ks < 4; ++ks) {
    const int k0 = ks * 32 + q * 8;
    s16x8 af[4];
#pragma unroll
    for (int rt = 0; rt < 4; ++rt) {
      long r = rowbase + rt * 16 + cl;
      if (r >= VOCAB) r = VOCAB - 1;      // tail clamp (dup loads, stores masked)
      const float* ap = emb + r * EDIM + k0;
      f32x4 a0 = *(const f32x4*)ap;
      f32x4 a1 = *(const f32x4*)(ap + 4);
      u16x8 t;
      t[0] = f2bf(a0[0]); t[1] = f2bf(a0[1]); t[2] = f2bf(a0[2]); t[3] = f2bf(a0[3]);
      t[4] = f2bf(a1[0]); t[5] = f2bf(a1[1]); t[6] = f2bf(a1[2]); t[7] = f2bf(a1[3]);
      af[rt] = __builtin_bit_cast(s16x8, t);
    }
#pragma unroll
    for (int nt = 0; nt < 8; ++nt) {
      s16x8 bf = *(const s16x8*)&WT[nt * 16 + cl][k0];
#pragma unroll
      for (int rt = 0; rt < 4; ++rt)
        acc[rt][nt] = __builtin_amdgcn_mfma_f32_16x16x32_bf16(af[rt], bf, acc[rt][nt], 0, 0, 0);
    }
  }

#pragma unroll
  for (int rt = 0; rt < 4; ++rt) {
#pragma unroll
    for (int nt = 0; nt < 8; ++nt) {
      const int col = nt * 16 + cl;
      const float bv = bsh[col];
#pragma unroll
      for (int r = 0; r < 4; ++r) {
        long row = rowbase + rt * 16 + q * 4 + r;
        if (row < VOCAB) T[row * EDIM + col] = f2bf(acc[rt][nt][r] + bv);
      }
    }
  }
}

// ---------------- Kernel 2: per-tree gather + bottom-up subtree sums + max ----------------
// v2: one block = one (tree, dim-half). P[512][64] bf16 = 64 KiB -> 2 blocks/CU,
// 16 waves/CU (50% occupancy vs 18% in v1). Each half-row is one 128B cache line.
__global__ __launch_bounds__(512) void tree_kernel(
    const unsigned short* __restrict__ T, const int* __restrict__ tokens,
    float* __restrict__ out) {
  __shared__ unsigned short P[512][64];  // 65536 B

  const int tid = threadIdx.x;
  const int bid = blockIdx.x;
  const int tree = bid & (NTREES - 1);
  const int half = bid >> 11;            // 0 or 1: dims [0,64) or [64,128)
  const int wv = tid >> 6, lane = tid & 63;
  const int n8 = lane >> 3;              // node-within-group-of-8
  const int c8 = lane & 7;               // 16B chunk within the 128B half-row

  // --- gather phase: prefetch tokens, then 8 LDS-DMA loads per wave (8 rows each) ---
  const int* tk = tokens + (long)tree * KNODES;
  int toks[8];
#pragma unroll
  for (int i = 0; i < 8; ++i) {
    int node = wv * 64 + i * 8 + n8;
    toks[i] = tk[node > 510 ? 510 : node];  // row 511 = dup of 510, never read
  }
#pragma unroll
  for (int i = 0; i < 8; ++i) {
    const unsigned short* src = T + (long)toks[i] * EDIM + half * 64 + c8 * 8;
    unsigned short* dst = &P[wv * 64 + i * 8][0];  // wave-uniform; HW adds lane*16
    __builtin_amdgcn_global_load_lds(
        (const __attribute__((address_space(1))) unsigned int*)src,
        (__attribute__((address_space(3))) unsigned int*)dst, 16, 0, 0);
  }
  __syncthreads();

  // --- tree phase: thread owns dim-chunk c (8 dims), node-group g (of 64) ---
  const int c = tid & 7, g = tid >> 3;
  float rmax[8];
#pragma unroll
  for (int e = 0; e < 8; ++e) rmax[e] = 0.f;  // 0-init folds the final ReLU clamp

  for (int l = 7; l >= 0; --l) {
    const int cnt = 1 << l;
    for (int j = g; j < cnt; j += 64) {
      const int m = cnt - 1 + j;
      u16x8 pm = *(const u16x8*)&P[m][c * 8];
      u16x8 c1 = *(const u16x8*)&P[2 * m + 1][c * 8];
      u16x8 c2 = *(const u16x8*)&P[2 * m + 2][c * 8];
      u16x8 sp;
#pragma unroll
      for (int e = 0; e < 8; ++e) {
        float x = bf2f(c1[e]), y = bf2f(c2[e]);
        float sv = bf2f(pm[e]) + x + y;
        rmax[e] = fmaxf(rmax[e], fmaxf(fmaxf(x, y), sv));  // children cover leaves
        sp[e] = f2bf(sv);
      }
      *(u16x8*)&P[m][c * 8] = sp;
    }
    __syncthreads();  // write range (< 2^{l+1}-1) disjoint from next level's reads
  }

  // --- max reduce across 64 node-groups (overlay scratch on dead P rows) ---
  float* mb = (float*)&P[0][0];  // 64*64*4 = 16 KiB << 64 KiB
#pragma unroll
  for (int e = 0; e < 8; ++e) mb[g * 64 + c * 8 + e] = rmax[e];
  __syncthreads();
  if (tid < 64) {
    float v = mb[tid];
#pragma unroll 4
    for (int g2 = 1; g2 < 64; ++g2) v = fmaxf(v, mb[g2 * 64 + tid]);
    out[(long)tree * 128 + half * 64 + tid] = v;
  }
}

extern "C" void kernel_launch(void* const* d_in, const int* in_sizes, int n_in,
                              void* d_out, int out_size, void* d_ws, size_t ws_size,
                              hipStream_t stream) {
  const float* emb = (const float*)d_in[0];
  const float* W = (const float*)d_in[1];
  const float* b = (const float*)d_in[2];
  const int* tokens = (const int*)d_in[3];
  // d_in[4..6] (parent/level/batch_id) are structural — recomputed from index math.

  unsigned short* T = (unsigned short*)d_ws;  // 200000*128*2 = 51.2 MB scratch
  float* out = (float*)d_out;

  const int nblk1 = (VOCAB + 255) / 256;  // 782
  proj_kernel<<<nblk1, 256, 0, stream>>>(emb, W, b, T);
  tree_kernel<<<NTREES * 2, 512, 0, stream>>>(T, tokens, out);
}